// Round 11
// baseline (484.853 us; speedup 1.0000x reference)
//
#include <hip/hip_runtime.h>
#include <hip/hip_cooperative_groups.h>
#include <stdint.h>

namespace cg = cooperative_groups;

// ---------------------------------------------------------------------------
// DkNN round 15: single cooperative dispatch fusing the three VERIFIED R9
// phases (prep -> grid.sync -> mfma -> grid.sync -> select_classify), to
// eliminate the ~100-150us inter-dispatch residual that top-5 censoring
// proves is not inside any one kernel. Phase bodies are copies of R9's
// verified kernels; grid-stride loops are block-uniform; vb&7==bid&7
// preserves the XCD swizzle. Fallback: if cooperative launch unavailable,
// run the three R9 kernels unchanged (= the 304.8us baseline).
// ---------------------------------------------------------------------------

typedef __attribute__((ext_vector_type(8))) short short8;   // 8 bf16 = 4 VGPR
typedef __attribute__((ext_vector_type(4))) float float4v;  // MFMA C/D

static __device__ __forceinline__ unsigned short bf16_rn(float f) {
    unsigned int u = __float_as_uint(f);
    unsigned int r = (u + 0x7FFFu + ((u >> 16) & 1u)) >> 16;
    return (unsigned short)r;
}

static __device__ __forceinline__ void gload_lds16(const void* g, void* l) {
    __builtin_amdgcn_global_load_lds(
        (const __attribute__((address_space(1))) unsigned int*)g,
        (__attribute__((address_space(3))) unsigned int*)l, 16, 0, 0);
}

// ===========================================================================
// Fused cooperative kernel
// ===========================================================================
__global__ __launch_bounds__(256, 4) void dknn_fused(
    const float* __restrict__ x, const float* __restrict__ X,
    const float* __restrict__ center,
    const int* __restrict__ labels, const int* __restrict__ nbr,
    const int* __restrict__ cali, float* __restrict__ out,
    unsigned short* __restrict__ Ah, float* __restrict__ xqf,
    float* __restrict__ q2a, float* __restrict__ al2q,
    unsigned short* __restrict__ Bh, float* __restrict__ xn2,
    float* __restrict__ pmax, float* __restrict__ gmin,
    int Mp, int Np, int nb_train, int B,
    int ntiles, int nper, int mtiles, int train_rb,
    int knm1, int nb_cali)
{
    __shared__ unsigned short As[128 * 64];   // phase2 A-tile / phase3 gbuf
    __shared__ unsigned short Bs[128 * 64];   // phase2 B-tile / phase3 xq_s
    __shared__ float p1[4], p2[4], p3[4], sm[4];
    __shared__ float wmin[4], wpm[4], fsc[4];
    __shared__ int   fid[4];
    __shared__ int   cand[256];
    __shared__ float s_thr;
    __shared__ int   s_ncand, s_closest;

    const int tid  = threadIdx.x;
    const int nblk = gridDim.x;
    cg::grid_group grid = cg::this_grid();

    // ================= PHASE 1: prep (R9 prep_all body) =================
    {
        const int nvb = train_rb + Mp;
        for (int vb = blockIdx.x; vb < nvb; vb += nblk) {
            __syncthreads();   // protect shared partials across iterations
            if (vb < train_rb) {
                const int seg = tid & 15;
                const int rq  = tid >> 4;
                const int r0  = vb * 64 + rq * 4;
                float4 v[4][4];
                bool ok[4];
                #pragma unroll
                for (int rr = 0; rr < 4; ++rr) {
                    ok[rr] = (r0 + rr < nb_train);
                    if (ok[rr]) {
                        const float4* s = (const float4*)(X + (size_t)(r0 + rr) * 256 + seg * 16);
                        v[rr][0] = s[0]; v[rr][1] = s[1]; v[rr][2] = s[2]; v[rr][3] = s[3];
                    }
                }
                float ss[4];
                #pragma unroll
                for (int rr = 0; rr < 4; ++rr) {
                    if (ok[rr]) {
                        short8 h0, h1;
                        h0[0] = bf16_rn(v[rr][0].x); h0[1] = bf16_rn(v[rr][0].y);
                        h0[2] = bf16_rn(v[rr][0].z); h0[3] = bf16_rn(v[rr][0].w);
                        h0[4] = bf16_rn(v[rr][1].x); h0[5] = bf16_rn(v[rr][1].y);
                        h0[6] = bf16_rn(v[rr][1].z); h0[7] = bf16_rn(v[rr][1].w);
                        h1[0] = bf16_rn(v[rr][2].x); h1[1] = bf16_rn(v[rr][2].y);
                        h1[2] = bf16_rn(v[rr][2].z); h1[3] = bf16_rn(v[rr][2].w);
                        h1[4] = bf16_rn(v[rr][3].x); h1[5] = bf16_rn(v[rr][3].y);
                        h1[6] = bf16_rn(v[rr][3].z); h1[7] = bf16_rn(v[rr][3].w);
                        unsigned short* bp = Bh + (size_t)(r0 + rr) * 256 + seg * 16;
                        *(short8*)bp = h0;
                        *(short8*)(bp + 8) = h1;
                        ss[rr] = v[rr][0].x * v[rr][0].x + v[rr][0].y * v[rr][0].y
                               + v[rr][0].z * v[rr][0].z + v[rr][0].w * v[rr][0].w
                               + v[rr][1].x * v[rr][1].x + v[rr][1].y * v[rr][1].y
                               + v[rr][1].z * v[rr][1].z + v[rr][1].w * v[rr][1].w
                               + v[rr][2].x * v[rr][2].x + v[rr][2].y * v[rr][2].y
                               + v[rr][2].z * v[rr][2].z + v[rr][2].w * v[rr][2].w
                               + v[rr][3].x * v[rr][3].x + v[rr][3].y * v[rr][3].y
                               + v[rr][3].z * v[rr][3].z + v[rr][3].w * v[rr][3].w;
                    } else {
                        short8 z = {0, 0, 0, 0, 0, 0, 0, 0};
                        unsigned short* bp = Bh + (size_t)(r0 + rr) * 256 + seg * 16;
                        *(short8*)bp = z;
                        *(short8*)(bp + 8) = z;
                        ss[rr] = 0.f;
                    }
                }
                #pragma unroll
                for (int s = 1; s < 16; s <<= 1) {
                    ss[0] += __shfl_xor(ss[0], s);
                    ss[1] += __shfl_xor(ss[1], s);
                    ss[2] += __shfl_xor(ss[2], s);
                    ss[3] += __shfl_xor(ss[3], s);
                }
                float mx = 0.f;
                if (seg == 0) {
                    #pragma unroll
                    for (int rr = 0; rr < 4; ++rr) mx = fmaxf(mx, ok[rr] ? ss[rr] : 0.f);
                    if (ok[3]) {
                        *(float4*)(xn2 + r0) = make_float4(ss[0], ss[1], ss[2], ss[3]);
                    } else {
                        #pragma unroll
                        for (int rr = 0; rr < 4; ++rr)
                            xn2[r0 + rr] = ok[rr] ? ss[rr] : 3.0e38f;
                    }
                }
                #pragma unroll
                for (int s = 1; s < 64; s <<= 1) mx = fmaxf(mx, __shfl_xor(mx, s));
                if ((tid & 63) == 0) sm[tid >> 6] = mx;
                __syncthreads();
                if (tid == 0)
                    pmax[vb] = fmaxf(fmaxf(sm[0], sm[1]), fmaxf(sm[2], sm[3]));
            } else {
                const int row = vb - train_rb;
                if (row >= B) {
                    Ah[(size_t)row * 256 + tid] = 0;
                    xqf[(size_t)row * 256 + tid] = 0.f;
                    if (tid == 0) { q2a[row] = 0.f; al2q[row] = 0.f; }
                    continue;
                }
                float v = x[(size_t)row * 256 + tid];
                float ss = v * v;
                #pragma unroll
                for (int s = 1; s < 64; s <<= 1) ss += __shfl_xor(ss, s);
                if ((tid & 63) == 0) p1[tid >> 6] = ss;
                __syncthreads();
                float tot = p1[0] + p1[1] + p1[2] + p1[3];
                float inv = 1.0f / sqrtf(tot);
                float val = v * inv - center[tid];
                unsigned short hb = bf16_rn(val);
                float hf = __uint_as_float((unsigned int)hb << 16);
                float al = val - hf;
                Ah[(size_t)row * 256 + tid] = hb;
                xqf[(size_t)row * 256 + tid] = val;
                float ss2 = val * val, sal = al * al;
                #pragma unroll
                for (int s = 1; s < 64; s <<= 1) {
                    ss2 += __shfl_xor(ss2, s);
                    sal += __shfl_xor(sal, s);
                }
                if ((tid & 63) == 0) { p2[tid >> 6] = ss2; p3[tid >> 6] = sal; }
                __syncthreads();
                if (tid == 0) {
                    q2a[row]  = p2[0] + p2[1] + p2[2] + p2[3];
                    al2q[row] = p3[0] + p3[1] + p3[2] + p3[3];
                }
            }
        }
    }
    grid.sync();

    // ================= PHASE 2: GEMM (R9 mfma_tile body) =================
    {
        const int ntot = 8 * nper * mtiles;
        const int wave = tid >> 6;
        const int lane = tid & 63;
        const int ng64 = Np >> 6;
        for (int vb = blockIdx.x; vb < ntot; vb += nblk) {
            const int xcd = vb & 7;
            const int s_  = vb >> 3;
            const int n_t = xcd * nper + (s_ / mtiles);
            const int m_t = s_ - (s_ / mtiles) * mtiles;
            if (n_t >= ntiles) continue;
            const int mtile = m_t * 128;
            const int ntile = n_t * 128;

            const int isB    = wave >> 1;
            const int Rwave  = (wave & 1) * 64;
            const int lrow8  = lane >> 3;
            const int lchunk = lane & 7;
            const unsigned short* sbase = isB
                ? (Bh + (size_t)(ntile + Rwave + lrow8) * 256 + (size_t)((lchunk ^ lrow8) * 8))
                : (Ah + (size_t)(mtile + Rwave + lrow8) * 256 + (size_t)((lchunk ^ lrow8) * 8));
            unsigned short* lwave = (isB ? Bs : As) + Rwave * 64;

            const int mq = (wave >> 1) * 64;
            const int nq = (wave & 1) * 64;
            const int lrow = lane & 15;
            const int kseg = lane >> 4;
            const int sw = lrow & 7;

            float4v acc[4][4];
            #pragma unroll
            for (int i = 0; i < 4; ++i)
                #pragma unroll
                for (int j = 0; j < 4; ++j)
                    acc[i][j] = (float4v){0.f, 0.f, 0.f, 0.f};

            for (int s = 0; s < 4; ++s) {
                const unsigned short* g = sbase + (size_t)(s * 64);
                __syncthreads();
                #pragma unroll
                for (int q = 0; q < 8; ++q)
                    gload_lds16(g + q * 2048, lwave + q * 512);
                __syncthreads();
                #pragma unroll
                for (int t = 0; t < 2; ++t) {
                    const int wch = ((t * 4 + kseg) ^ sw) * 8;
                    short8 a[4], b[4];
                    #pragma unroll
                    for (int i = 0; i < 4; ++i)
                        a[i] = *(const short8*)&As[(mq + i * 16 + lrow) * 64 + wch];
                    #pragma unroll
                    for (int j = 0; j < 4; ++j)
                        b[j] = *(const short8*)&Bs[(nq + j * 16 + lrow) * 64 + wch];
                    #pragma unroll
                    for (int i = 0; i < 4; ++i)
                        #pragma unroll
                        for (int j = 0; j < 4; ++j)
                            acc[i][j] = __builtin_amdgcn_mfma_f32_16x16x32_bf16(
                                a[i], b[j], acc[i][j], 0, 0, 0);
                }
            }

            const int gb = (ntile + nq) >> 6;
            float xnv[4];
            #pragma unroll
            for (int j = 0; j < 4; ++j)
                xnv[j] = xn2[ntile + nq + j * 16 + lrow];   // pads hold 3e38

            #pragma unroll
            for (int i = 0; i < 4; ++i) {
                #pragma unroll
                for (int r = 0; r < 4; ++r) {
                    const int lm = mq + i * 16 + kseg * 4 + r;
                    const int gq = mtile + lm;
                    float vm = fminf(
                        fminf(xnv[0] - 2.0f * acc[i][0][r], xnv[1] - 2.0f * acc[i][1][r]),
                        fminf(xnv[2] - 2.0f * acc[i][2][r], xnv[3] - 2.0f * acc[i][3][r]));
                    #pragma unroll
                    for (int sft = 1; sft < 16; sft <<= 1)
                        vm = fminf(vm, __shfl_xor(vm, sft));
                    if (lrow == 0 && gq < B)
                        gmin[(size_t)gq * ng64 + gb] = vm;
                }
            }
        }
    }
    grid.sync();

    // ======= PHASE 3: select + classify (R9 select_classify body) =======
    {
        float* gbuf = (float*)As;          // ng64 <= 2048 floats fits 16KB
        float* xq_s = (float*)Bs;          // 256 floats
        const int lane = tid & 63;
        const int wave = tid >> 6;
        const int ng64 = Np >> 6;

        for (int q = blockIdx.x; q < B; q += nblk) {
            __syncthreads();
            if (tid == 0) s_ncand = 0;
            xq_s[tid] = xqf[(size_t)q * 256 + tid];
            float vmin = 3.4e38f;
            for (int i = tid; i < ng64; i += 256) {
                float v = gmin[(size_t)q * ng64 + i];
                gbuf[i] = v;
                vmin = fminf(vmin, v);
            }
            float pm = 0.f;
            for (int i = tid; i < train_rb; i += 256) pm = fmaxf(pm, pmax[i]);
            #pragma unroll
            for (int s = 1; s < 64; s <<= 1) {
                vmin = fminf(vmin, __shfl_xor(vmin, s));
                pm   = fmaxf(pm,   __shfl_xor(pm, s));
            }
            if (lane == 0) { wmin[wave] = vmin; wpm[wave] = pm; }
            __syncthreads();
            if (tid == 0) {
                float m = fminf(fminf(wmin[0], wmin[1]), fminf(wmin[2], wmin[3]));
                float mb2 = fmaxf(fmaxf(wpm[0], wpm[1]), fmaxf(wpm[2], wpm[3]));
                float maxb  = sqrtf(mb2);
                float maxbl = maxb * 0.00390625f;   // ||Bl|| <= 2^-8 ||B||
                float an = sqrtf(q2a[q]), al = sqrtf(al2q[q]);
                float errdot = al * maxb * 1.00390625f + (an + al) * maxbl;
                s_thr = m + 4.0f * errdot + 1e-3f;
            }
            __syncthreads();
            const float thr = s_thr;
            for (int g = tid; g < ng64; g += 256) {
                if (gbuf[g] <= thr) {
                    int p = atomicAdd(&s_ncand, 1);
                    if (p < 256) cand[p] = g;
                }
            }
            __syncthreads();
            const int nc = s_ncand;

            const int rsub = tid & 3;
            const int rrow = tid >> 2;
            float bsc = 3.4e38f; int bidx = 0x7FFFFFFF;
            auto rescore = [&](int g) {
                int row = g * 64 + rrow;
                if (row < nb_train) {
                    const float* xr = X + (size_t)row * 256 + rsub * 64;
                    const float* xs = xq_s + rsub * 64;
                    float dot = 0.f;
                    #pragma unroll
                    for (int k = 0; k < 16; ++k) {
                        float4 a4 = *(const float4*)(xs + k * 4);
                        float4 b4 = *(const float4*)(xr + k * 4);
                        dot += a4.x * b4.x + a4.y * b4.y + a4.z * b4.z + a4.w * b4.w;
                    }
                    dot += __shfl_xor(dot, 1);
                    dot += __shfl_xor(dot, 2);
                    float sc = xn2[row] - 2.0f * dot;
                    if (sc < bsc || (sc == bsc && row < bidx)) { bsc = sc; bidx = row; }
                }
            };
            if (nc <= 256) {
                for (int c = 0; c < nc; ++c) rescore(cand[c]);
            } else {
                for (int g = 0; g < ng64; ++g)
                    if (gbuf[g] <= thr) rescore(g);   // correctness backstop
            }
            #pragma unroll
            for (int s = 1; s < 64; s <<= 1) {
                float osc = __shfl_xor(bsc, s);
                int   oid = __shfl_xor(bidx, s);
                if (osc < bsc || (osc == bsc && oid < bidx)) { bsc = osc; bidx = oid; }
            }
            if (lane == 0) { fsc[wave] = bsc; fid[wave] = bidx; }
            __syncthreads();
            if (tid == 0) {
                float bs = fsc[0]; int bi = fid[0];
                #pragma unroll
                for (int w = 1; w < 4; ++w)
                    if (fsc[w] < bs || (fsc[w] == bs && fid[w] < bi)) { bs = fsc[w]; bi = fid[w]; }
                s_closest = bi;
            }
            __syncthreads();

            if (wave == 0) {
                const int closest = s_closest;
                const int K = knm1 + 1;   // 75
                int lbl0 = -1, lbl1 = -1;
                if (lane < K) {
                    int idx = (lane == 0) ? closest : nbr[(size_t)closest * knm1 + (lane - 1)];
                    lbl0 = labels[idx];
                }
                int j2 = lane + 64;
                if (j2 < K) {
                    int idx = nbr[(size_t)closest * knm1 + (j2 - 1)];
                    lbl1 = labels[idx];
                }
                int bestc = 0, bestp = -1;
                #pragma unroll
                for (int c = 0; c < 10; ++c) {
                    int cnt = __popcll(__ballot(lbl0 == c)) + __popcll(__ballot(lbl1 == c));
                    int v = K - cnt;
                    int lo = 0, hi = nb_cali;
                    while (lo < hi) {             // bisect_left
                        int mid = (lo + hi) >> 1;
                        if (cali[mid] < v) lo = mid + 1; else hi = mid;
                    }
                    int p = nb_cali - lo;
                    if (p > bestp) { bestp = p; bestc = c; }
                }
                float pv = (float)bestp / (float)nb_cali;
                if (lane < 10)
                    out[(size_t)q * 10 + lane] = (lane == bestc) ? pv : 0.0f;
            }
        }
    }
}

// ===========================================================================
// Fallback path: the three verified R9 kernels, unchanged.
// ===========================================================================
__global__ __launch_bounds__(256) void prep_all(
    const float* __restrict__ X, const float* __restrict__ x,
    const float* __restrict__ center,
    unsigned short* __restrict__ Bh, float* __restrict__ xn2,
    unsigned short* __restrict__ Ah, float* __restrict__ xqf,
    float* __restrict__ q2a, float* __restrict__ al2q,
    float* __restrict__ pmax,
    int nb_train, int Np, int B, int Mp, int train_rb)
{
    const int tid = threadIdx.x;
    __shared__ float sm[4];
    __shared__ float p1[4], p2[4], p3[4];

    if ((int)blockIdx.x < train_rb) {
        const int seg = tid & 15;
        const int rq  = tid >> 4;
        const int r0  = blockIdx.x * 64 + rq * 4;
        float4 v[4][4];
        bool ok[4];
        #pragma unroll
        for (int rr = 0; rr < 4; ++rr) {
            ok[rr] = (r0 + rr < nb_train);
            if (ok[rr]) {
                const float4* s = (const float4*)(X + (size_t)(r0 + rr) * 256 + seg * 16);
                v[rr][0] = s[0]; v[rr][1] = s[1]; v[rr][2] = s[2]; v[rr][3] = s[3];
            }
        }
        float ss[4];
        #pragma unroll
        for (int rr = 0; rr < 4; ++rr) {
            if (ok[rr]) {
                short8 h0, h1;
                h0[0] = bf16_rn(v[rr][0].x); h0[1] = bf16_rn(v[rr][0].y);
                h0[2] = bf16_rn(v[rr][0].z); h0[3] = bf16_rn(v[rr][0].w);
                h0[4] = bf16_rn(v[rr][1].x); h0[5] = bf16_rn(v[rr][1].y);
                h0[6] = bf16_rn(v[rr][1].z); h0[7] = bf16_rn(v[rr][1].w);
                h1[0] = bf16_rn(v[rr][2].x); h1[1] = bf16_rn(v[rr][2].y);
                h1[2] = bf16_rn(v[rr][2].z); h1[3] = bf16_rn(v[rr][2].w);
                h1[4] = bf16_rn(v[rr][3].x); h1[5] = bf16_rn(v[rr][3].y);
                h1[6] = bf16_rn(v[rr][3].z); h1[7] = bf16_rn(v[rr][3].w);
                unsigned short* bp = Bh + (size_t)(r0 + rr) * 256 + seg * 16;
                *(short8*)bp = h0;
                *(short8*)(bp + 8) = h1;
                ss[rr] = v[rr][0].x * v[rr][0].x + v[rr][0].y * v[rr][0].y
                       + v[rr][0].z * v[rr][0].z + v[rr][0].w * v[rr][0].w
                       + v[rr][1].x * v[rr][1].x + v[rr][1].y * v[rr][1].y
                       + v[rr][1].z * v[rr][1].z + v[rr][1].w * v[rr][1].w
                       + v[rr][2].x * v[rr][2].x + v[rr][2].y * v[rr][2].y
                       + v[rr][2].z * v[rr][2].z + v[rr][2].w * v[rr][2].w
                       + v[rr][3].x * v[rr][3].x + v[rr][3].y * v[rr][3].y
                       + v[rr][3].z * v[rr][3].z + v[rr][3].w * v[rr][3].w;
            } else {
                short8 z = {0, 0, 0, 0, 0, 0, 0, 0};
                unsigned short* bp = Bh + (size_t)(r0 + rr) * 256 + seg * 16;
                *(short8*)bp = z;
                *(short8*)(bp + 8) = z;
                ss[rr] = 0.f;
            }
        }
        #pragma unroll
        for (int s = 1; s < 16; s <<= 1) {
            ss[0] += __shfl_xor(ss[0], s);
            ss[1] += __shfl_xor(ss[1], s);
            ss[2] += __shfl_xor(ss[2], s);
            ss[3] += __shfl_xor(ss[3], s);
        }
        float mx = 0.f;
        if (seg == 0) {
            #pragma unroll
            for (int rr = 0; rr < 4; ++rr) mx = fmaxf(mx, ok[rr] ? ss[rr] : 0.f);
            if (ok[3]) {
                *(float4*)(xn2 + r0) = make_float4(ss[0], ss[1], ss[2], ss[3]);
            } else {
                #pragma unroll
                for (int rr = 0; rr < 4; ++rr)
                    xn2[r0 + rr] = ok[rr] ? ss[rr] : 3.0e38f;
            }
        }
        #pragma unroll
        for (int s = 1; s < 64; s <<= 1) mx = fmaxf(mx, __shfl_xor(mx, s));
        if ((tid & 63) == 0) sm[tid >> 6] = mx;
        __syncthreads();
        if (tid == 0)
            pmax[blockIdx.x] = fmaxf(fmaxf(sm[0], sm[1]), fmaxf(sm[2], sm[3]));
        return;
    }
    int row = blockIdx.x - train_rb;
    if (row >= Mp) return;
    if (row >= B) {
        Ah[(size_t)row * 256 + tid] = 0;
        xqf[(size_t)row * 256 + tid] = 0.f;
        if (tid == 0) { q2a[row] = 0.f; al2q[row] = 0.f; }
        return;
    }
    float v = x[(size_t)row * 256 + tid];
    float ss = v * v;
    #pragma unroll
    for (int s = 1; s < 64; s <<= 1) ss += __shfl_xor(ss, s);
    if ((tid & 63) == 0) p1[tid >> 6] = ss;
    __syncthreads();
    float tot = p1[0] + p1[1] + p1[2] + p1[3];
    float inv = 1.0f / sqrtf(tot);
    float val = v * inv - center[tid];
    unsigned short hb = bf16_rn(val);
    float hf = __uint_as_float((unsigned int)hb << 16);
    float al = val - hf;
    Ah[(size_t)row * 256 + tid] = hb;
    xqf[(size_t)row * 256 + tid] = val;
    float ss2 = val * val, sal = al * al;
    #pragma unroll
    for (int s = 1; s < 64; s <<= 1) {
        ss2 += __shfl_xor(ss2, s);
        sal += __shfl_xor(sal, s);
    }
    if ((tid & 63) == 0) { p2[tid >> 6] = ss2; p3[tid >> 6] = sal; }
    __syncthreads();
    if (tid == 0) {
        q2a[row]  = p2[0] + p2[1] + p2[2] + p2[3];
        al2q[row] = p3[0] + p3[1] + p3[2] + p3[3];
    }
}

__global__ __launch_bounds__(256, 4) void mfma_tile(
    const unsigned short* __restrict__ Adata,
    const unsigned short* __restrict__ Bdata,
    const float* __restrict__ xn2,
    float* __restrict__ gmin,
    int Mp, int Np, int nb_train, int B,
    int ntiles, int nper, int mtiles)
{
    __shared__ unsigned short As[128 * 64];
    __shared__ unsigned short Bs[128 * 64];

    const int bid = blockIdx.x;
    const int xcd = bid & 7;
    const int s_  = bid >> 3;
    const int n_t = xcd * nper + (s_ / mtiles);
    const int m_t = s_ - (s_ / mtiles) * mtiles;
    if (n_t >= ntiles) return;
    const int mtile = m_t * 128;
    const int ntile = n_t * 128;

    const int tid  = threadIdx.x;
    const int wave = tid >> 6;
    const int lane = tid & 63;

    const int isB   = wave >> 1;
    const int Rwave = (wave & 1) * 64;
    const int lrow8  = lane >> 3;
    const int lchunk = lane & 7;
    const unsigned short* sbase = isB
        ? (Bdata + (size_t)(ntile + Rwave + lrow8) * 256 + (size_t)((lchunk ^ lrow8) * 8))
        : (Adata + (size_t)(mtile + Rwave + lrow8) * 256 + (size_t)((lchunk ^ lrow8) * 8));
    unsigned short* lwave = (isB ? Bs : As) + Rwave * 64;

    const int mq = (wave >> 1) * 64;
    const int nq = (wave & 1) * 64;
    const int lrow = lane & 15;
    const int kseg = lane >> 4;
    const int sw = lrow & 7;

    float4v acc[4][4];
    #pragma unroll
    for (int i = 0; i < 4; ++i)
        #pragma unroll
        for (int j = 0; j < 4; ++j)
            acc[i][j] = (float4v){0.f, 0.f, 0.f, 0.f};

    for (int s = 0; s < 4; ++s) {
        const unsigned short* g = sbase + (size_t)(s * 64);
        __syncthreads();
        #pragma unroll
        for (int q = 0; q < 8; ++q)
            gload_lds16(g + q * 2048, lwave + q * 512);
        __syncthreads();
        #pragma unroll
        for (int t = 0; t < 2; ++t) {
            const int wch = ((t * 4 + kseg) ^ sw) * 8;
            short8 a[4], b[4];
            #pragma unroll
            for (int i = 0; i < 4; ++i)
                a[i] = *(const short8*)&As[(mq + i * 16 + lrow) * 64 + wch];
            #pragma unroll
            for (int j = 0; j < 4; ++j)
                b[j] = *(const short8*)&Bs[(nq + j * 16 + lrow) * 64 + wch];
            #pragma unroll
            for (int i = 0; i < 4; ++i)
                #pragma unroll
                for (int j = 0; j < 4; ++j)
                    acc[i][j] = __builtin_amdgcn_mfma_f32_16x16x32_bf16(
                        a[i], b[j], acc[i][j], 0, 0, 0);
        }
    }

    const int ng64 = Np >> 6;
    const int gb = (ntile + nq) >> 6;
    float xnv[4];
    #pragma unroll
    for (int j = 0; j < 4; ++j)
        xnv[j] = xn2[ntile + nq + j * 16 + lrow];

    #pragma unroll
    for (int i = 0; i < 4; ++i) {
        #pragma unroll
        for (int r = 0; r < 4; ++r) {
            const int lm = mq + i * 16 + kseg * 4 + r;
            const int gq = mtile + lm;
            float vm = fminf(
                fminf(xnv[0] - 2.0f * acc[i][0][r], xnv[1] - 2.0f * acc[i][1][r]),
                fminf(xnv[2] - 2.0f * acc[i][2][r], xnv[3] - 2.0f * acc[i][3][r]));
            #pragma unroll
            for (int sft = 1; sft < 16; sft <<= 1)
                vm = fminf(vm, __shfl_xor(vm, sft));
            if (lrow == 0 && gq < B)
                gmin[(size_t)gq * ng64 + gb] = vm;
        }
    }
}

__global__ __launch_bounds__(256) void select_classify(
    const float* __restrict__ gmin, const float* __restrict__ xqf,
    const float* __restrict__ X, const float* __restrict__ xn2,
    const float* __restrict__ q2a, const float* __restrict__ al2q,
    const float* __restrict__ pmax,
    const int* __restrict__ labels, const int* __restrict__ nbr,
    const int* __restrict__ cali, float* __restrict__ out,
    int Np, int nb_train, int knm1, int nb_cali, int B, int train_rb)
{
    extern __shared__ float gbuf[];
    __shared__ float xq_s[256];
    __shared__ float wmin[4], wpm[4], fsc[4];
    __shared__ int   fid[4];
    __shared__ float s_thr;
    __shared__ int   cand[256];
    __shared__ int   s_ncand;
    __shared__ int   s_closest;

    const int q    = blockIdx.x;
    const int tid  = threadIdx.x;
    const int lane = tid & 63;
    const int wave = tid >> 6;
    const int ng64 = Np >> 6;

    if (tid == 0) s_ncand = 0;
    xq_s[tid] = xqf[(size_t)q * 256 + tid];
    float vmin = 3.4e38f;
    for (int i = tid; i < ng64; i += 256) {
        float v = gmin[(size_t)q * ng64 + i];
        gbuf[i] = v;
        vmin = fminf(vmin, v);
    }
    float pm = 0.f;
    for (int i = tid; i < train_rb; i += 256) pm = fmaxf(pm, pmax[i]);
    #pragma unroll
    for (int s = 1; s < 64; s <<= 1) {
        vmin = fminf(vmin, __shfl_xor(vmin, s));
        pm   = fmaxf(pm,   __shfl_xor(pm, s));
    }
    if (lane == 0) { wmin[wave] = vmin; wpm[wave] = pm; }
    __syncthreads();
    if (tid == 0) {
        float m = fminf(fminf(wmin[0], wmin[1]), fminf(wmin[2], wmin[3]));
        float mb2 = fmaxf(fmaxf(wpm[0], wpm[1]), fmaxf(wpm[2], wpm[3]));
        float maxb  = sqrtf(mb2);
        float maxbl = maxb * 0.00390625f;
        float an = sqrtf(q2a[q]), al = sqrtf(al2q[q]);
        float errdot = al * maxb * 1.00390625f + (an + al) * maxbl;
        s_thr = m + 4.0f * errdot + 1e-3f;
    }
    __syncthreads();
    const float thr = s_thr;
    for (int g = tid; g < ng64; g += 256) {
        if (gbuf[g] <= thr) {
            int p = atomicAdd(&s_ncand, 1);
            if (p < 256) cand[p] = g;
        }
    }
    __syncthreads();
    const int nc = s_ncand;

    const int rsub = tid & 3;
    const int rrow = tid >> 2;
    float bsc = 3.4e38f; int bidx = 0x7FFFFFFF;
    auto rescore = [&](int g) {
        int row = g * 64 + rrow;
        if (row < nb_train) {
            const float* xr = X + (size_t)row * 256 + rsub * 64;
            const float* xs = xq_s + rsub * 64;
            float dot = 0.f;
            #pragma unroll
            for (int k = 0; k < 16; ++k) {
                float4 a4 = *(const float4*)(xs + k * 4);
                float4 b4 = *(const float4*)(xr + k * 4);
                dot += a4.x * b4.x + a4.y * b4.y + a4.z * b4.z + a4.w * b4.w;
            }
            dot += __shfl_xor(dot, 1);
            dot += __shfl_xor(dot, 2);
            float sc = xn2[row] - 2.0f * dot;
            if (sc < bsc || (sc == bsc && row < bidx)) { bsc = sc; bidx = row; }
        }
    };
    if (nc <= 256) {
        for (int c = 0; c < nc; ++c) rescore(cand[c]);
    } else {
        for (int g = 0; g < ng64; ++g)
            if (gbuf[g] <= thr) rescore(g);
    }
    #pragma unroll
    for (int s = 1; s < 64; s <<= 1) {
        float osc = __shfl_xor(bsc, s);
        int   oid = __shfl_xor(bidx, s);
        if (osc < bsc || (osc == bsc && oid < bidx)) { bsc = osc; bidx = oid; }
    }
    if (lane == 0) { fsc[wave] = bsc; fid[wave] = bidx; }
    __syncthreads();
    if (tid == 0) {
        float bs = fsc[0]; int bi = fid[0];
        #pragma unroll
        for (int w = 1; w < 4; ++w)
            if (fsc[w] < bs || (fsc[w] == bs && fid[w] < bi)) { bs = fsc[w]; bi = fid[w]; }
        s_closest = bi;
    }
    __syncthreads();

    if (wave == 0) {
        const int closest = s_closest;
        const int K = knm1 + 1;
        int lbl0 = -1, lbl1 = -1;
        if (lane < K) {
            int idx = (lane == 0) ? closest : nbr[(size_t)closest * knm1 + (lane - 1)];
            lbl0 = labels[idx];
        }
        int j2 = lane + 64;
        if (j2 < K) {
            int idx = nbr[(size_t)closest * knm1 + (j2 - 1)];
            lbl1 = labels[idx];
        }
        int bestc = 0, bestp = -1;
        #pragma unroll
        for (int c = 0; c < 10; ++c) {
            int cnt = __popcll(__ballot(lbl0 == c)) + __popcll(__ballot(lbl1 == c));
            int v = K - cnt;
            int lo = 0, hi = nb_cali;
            while (lo < hi) {
                int mid = (lo + hi) >> 1;
                if (cali[mid] < v) lo = mid + 1; else hi = mid;
            }
            int p = nb_cali - lo;
            if (p > bestp) { bestp = p; bestc = c; }
        }
        float pv = (float)bestp / (float)nb_cali;
        if (lane < 10)
            out[(size_t)q * 10 + lane] = (lane == bestc) ? pv : 0.0f;
    }
}

extern "C" void kernel_launch(void* const* d_in, const int* in_sizes, int n_in,
                              void* d_out, int out_size, void* d_ws, size_t ws_size,
                              hipStream_t stream) {
    const float* x      = (const float*)d_in[0];
    const float* X      = (const float*)d_in[1];
    const float* center = (const float*)d_in[2];
    const int* labels   = (const int*)d_in[3];
    const int* nbr      = (const int*)d_in[4];
    const int* cali     = (const int*)d_in[5];
    float* out = (float*)d_out;

    const int d        = in_sizes[2];              // 256
    int B        = in_sizes[0] / d;                // 1024
    int nb_train = in_sizes[3];                    // 100000
    int knm1     = in_sizes[4] / nb_train;         // 74
    int nb_cali  = in_sizes[5];                    // 1000

    int Mp = (B + 127) & ~127;                     // 1024
    int Np = (nb_train + 127) & ~127;              // 100096
    const int ng64 = Np >> 6;                      // 1564
    int ntiles = Np / 128;                         // 782
    int mtiles = Mp / 128;                         // 8
    int nper   = (ntiles + 7) / 8;                 // 98
    int train_rb = Np / 64;                        // 1564

    char* ws = (char*)d_ws;
    size_t off = 0;
    float* gmin = (float*)(ws + off);          off += (size_t)Mp * ng64 * 4;
    unsigned short* Ah = (unsigned short*)(ws + off); off += (size_t)Mp * 256 * 2;
    float* xqf  = (float*)(ws + off);          off += (size_t)Mp * 256 * 4;
    float* q2a  = (float*)(ws + off);          off += (size_t)Mp * 4;
    float* al2q = (float*)(ws + off);          off += (size_t)Mp * 4;
    unsigned short* Bh = (unsigned short*)(ws + off); off += (size_t)Np * 256 * 2;
    float* xn2  = (float*)(ws + off);          off += (size_t)Np * 4;
    float* pmax = (float*)(ws + off);          off += (size_t)train_rb * 4;

    // ---- cooperative capacity (queried once; queries don't enqueue work) ----
    static int coop_grid = -2;
    if (coop_grid == -2) {
        int maxb = 0;
        hipError_t e = hipOccupancyMaxActiveBlocksPerMultiprocessor(
            &maxb, dknn_fused, 256, 0);
        if (e == hipSuccess && maxb > 0) {
            hipDeviceProp_t prop;
            int dev = 0;
            hipGetDevice(&dev);
            if (hipGetDeviceProperties(&prop, dev) == hipSuccess) {
                int cap = maxb * prop.multiProcessorCount;
                coop_grid = cap < 1024 ? cap : 1024;
            } else {
                coop_grid = -1;
            }
        } else {
            coop_grid = -1;
        }
        if (coop_grid == 0) coop_grid = -1;
    }

    bool done = false;
    if (coop_grid > 0) {
        void* args[] = {
            (void*)&x, (void*)&X, (void*)&center, (void*)&labels, (void*)&nbr,
            (void*)&cali, (void*)&out, (void*)&Ah, (void*)&xqf, (void*)&q2a,
            (void*)&al2q, (void*)&Bh, (void*)&xn2, (void*)&pmax, (void*)&gmin,
            (void*)&Mp, (void*)&Np, (void*)&nb_train, (void*)&B, (void*)&ntiles,
            (void*)&nper, (void*)&mtiles, (void*)&train_rb, (void*)&knm1,
            (void*)&nb_cali
        };
        hipError_t err = hipLaunchCooperativeKernel(
            reinterpret_cast<void*>(dknn_fused), dim3(coop_grid), dim3(256),
            args, 0, stream);
        if (err == hipSuccess) done = true;
        else coop_grid = -1;   // permanent fallback
    }

    if (!done) {
        prep_all<<<train_rb + Mp, 256, 0, stream>>>(
            X, x, center, Bh, xn2, Ah, xqf, q2a, al2q, pmax,
            nb_train, Np, B, Mp, train_rb);
        mfma_tile<<<8 * nper * mtiles, 256, 0, stream>>>(
            Ah, Bh, xn2, gmin, Mp, Np, nb_train, B, ntiles, nper, mtiles);
        select_classify<<<B, 256, ng64 * 4, stream>>>(
            gmin, xqf, X, xn2, q2a, al2q, pmax, labels, nbr, cali, out,
            Np, nb_train, knm1, nb_cali, B, train_rb);
    }
}